// Round 2
// baseline (628.340 us; speedup 1.0000x reference)
//
#include <hip/hip_runtime.h>
#include <hip/hip_bf16.h>
#include <stdint.h>

#define DMODEL 1024
#define NEXP 32
#define ESZ 256
#define NTOK 8192
#define NH 4

typedef __hip_bfloat16 bf16;
typedef short bf16x8 __attribute__((ext_vector_type(8)));
typedef float f32x4 __attribute__((ext_vector_type(4)));

__device__ __forceinline__ void pack8(const float4& a, const float4& b, bf16* t) {
    t[0] = __float2bfloat16(a.x); t[1] = __float2bfloat16(a.y);
    t[2] = __float2bfloat16(a.z); t[3] = __float2bfloat16(a.w);
    t[4] = __float2bfloat16(b.x); t[5] = __float2bfloat16(b.y);
    t[6] = __float2bfloat16(b.z); t[7] = __float2bfloat16(b.w);
}

// async global -> LDS, 16 B per lane. LDS dest is wave-uniform base + lane*16.
__device__ __forceinline__ void gl_lds16(const void* g, void* l) {
    __builtin_amdgcn_global_load_lds(
        (const __attribute__((address_space(1))) uint32_t*)g,
        (__attribute__((address_space(3))) uint32_t*)l, 16, 0, 0);
}

// ---------------- x f32 -> bf16 (hoists conversion out of the GEMM hot loop) ----------------
__global__ void xconv_kernel(const float* __restrict__ x, bf16* __restrict__ xb) {
    size_t i = ((size_t)blockIdx.x * 256 + threadIdx.x) * 8;
    float4 a = *(const float4*)(x + i);
    float4 b = *(const float4*)(x + i + 4);
    bf16 t8[8];
    pack8(a, b, t8);
    *(uint4*)(xb + i) = *(uint4*)t8;
}

// ---------------- selection (pure f32): logits -> top-4 -> gates (NO atomics) ----------------
__global__ void sel_kernel(const float* __restrict__ x, const float* __restrict__ esel,
                           int* __restrict__ eidx, float* __restrict__ egate) {
    int lane = threadIdx.x & 63;
    int wid = threadIdx.x >> 6;
    int t = blockIdx.x * 4 + wid;

    const float* xp = x + (size_t)t * DMODEL + lane * 16;
    float xv[16];
    *(float4*)&xv[0]  = *(const float4*)(xp);
    *(float4*)&xv[4]  = *(const float4*)(xp + 4);
    *(float4*)&xv[8]  = *(const float4*)(xp + 8);
    *(float4*)&xv[12] = *(const float4*)(xp + 12);

    __shared__ float sc[4][NEXP];
    for (int e = 0; e < NEXP; ++e) {
        const float* sp = esel + (size_t)e * DMODEL + lane * 16;
        float4 p0 = *(const float4*)(sp);
        float4 p1 = *(const float4*)(sp + 4);
        float4 p2 = *(const float4*)(sp + 8);
        float4 p3 = *(const float4*)(sp + 12);
        float s = xv[0]*p0.x + xv[1]*p0.y + xv[2]*p0.z + xv[3]*p0.w
                + xv[4]*p1.x + xv[5]*p1.y + xv[6]*p1.z + xv[7]*p1.w
                + xv[8]*p2.x + xv[9]*p2.y + xv[10]*p2.z + xv[11]*p2.w
                + xv[12]*p3.x + xv[13]*p3.y + xv[14]*p3.z + xv[15]*p3.w;
        #pragma unroll
        for (int o = 32; o > 0; o >>= 1) s += __shfl_xor(s, o, 64);
        if (lane == 0) sc[wid][e] = s;
    }

    if (lane == 0) {
        for (int j = 0; j < NH; ++j) {
            float m = -1e30f; int mi = 0;
            for (int e = 0; e < NEXP; ++e) {
                float v = sc[wid][e];
                if (v > m) { m = v; mi = e; }
            }
            sc[wid][mi] = -1e30f;
            float g = 1.f / (1.f + expf(-m));
            eidx[t * NH + j] = mi;
            egate[t * NH + j] = g;
        }
    }
}

// ---------------- per-expert histogram (contention-free) ----------------
__global__ void hist_kernel(const int* __restrict__ eidx, int* __restrict__ counts,
                            int* __restrict__ counts_q) {
    int e = blockIdx.x;
    int w = threadIdx.x >> 6;
    int lane = threadIdx.x & 63;
    const int* p = eidx + w * 8192;
    int cnt = 0;
    for (int it = 0; it < 128; ++it)
        cnt += (p[it * 64 + lane] == e);
    #pragma unroll
    for (int o = 32; o > 0; o >>= 1) cnt += __shfl_xor(cnt, o, 64);
    __shared__ int s_q[4];
    if (lane == 0) s_q[w] = cnt;
    __syncthreads();
    if (threadIdx.x == 0) {
        counts[e] = s_q[0] + s_q[1] + s_q[2] + s_q[3];
        counts_q[e * 4 + 0] = s_q[0];
        counts_q[e * 4 + 1] = s_q[1];
        counts_q[e * 4 + 2] = s_q[2];
        counts_q[e * 4 + 3] = s_q[3];
    }
}

// ---------------- tiny exclusive scan ----------------
__global__ void scan_kernel(const int* __restrict__ counts, int* __restrict__ offsets) {
    if (threadIdx.x == 0) {
        int s = 0;
        for (int e = 0; e < NEXP; ++e) { offsets[e] = s; s += counts[e]; }
    }
}

// ---------------- deterministic ballot compaction (NO atomics) ----------------
__global__ void compact_kernel(const int* __restrict__ eidx, const float* __restrict__ egate,
                               const int* __restrict__ offsets, const int* __restrict__ counts_q,
                               int* __restrict__ btok, float* __restrict__ bgate) {
    int e = blockIdx.x;
    int q = blockIdx.y;
    int lane = threadIdx.x;
    int base = offsets[e];
    #pragma unroll
    for (int k = 0; k < 4; ++k) if (k < q) base += counts_q[e * 4 + k];
    const int* p = eidx + q * 8192;
    const float* g = egate + q * 8192;
    int v = p[lane];
    for (int it = 0; it < 128; ++it) {
        int v_next = (it < 127) ? p[(it + 1) * 64 + lane] : 0;
        unsigned long long m = __ballot(v == e);
        if (v == e) {
            int i = it * 64 + lane;
            int pos = base + __popcll(m & ((1ull << lane) - 1ull));
            btok[pos] = (q * 8192 + i) >> 2;
            bgate[pos] = g[i];
        }
        base += __popcll(m);
        v = v_next;
    }
}

// ---------------- per-expert transpose+convert: f32 in[e][R][C] -> bf16 out[e][C][R] ----------------
__global__ void transpose_conv_kernel(const float* __restrict__ in, bf16* __restrict__ out,
                                      int R, int C) {
    __shared__ bf16 tile[64][72];
    int e = blockIdx.z, tr = blockIdx.y, tc = blockIdx.x;
    const float* src = in + ((size_t)e * R + tr * 64) * C + tc * 64;
    #pragma unroll
    for (int i = 0; i < 2; ++i) {
        int c = threadIdx.x + 256 * i;
        int r = c >> 3, c8 = c & 7;
        float4 p0 = *(const float4*)(src + (size_t)r * C + c8 * 8);
        float4 p1 = *(const float4*)(src + (size_t)r * C + c8 * 8 + 4);
        bf16 t8[8];
        pack8(p0, p1, t8);
        *(uint4*)&tile[r][c8 * 8] = *(uint4*)t8;
    }
    __syncthreads();
    bf16* dst = out + ((size_t)e * C + tc * 64) * R + tr * 64;
    #pragma unroll
    for (int i = 0; i < 2; ++i) {
        int c = threadIdx.x + 256 * i;
        int oc = c >> 3, c8 = c & 7;
        bf16 tmp[8];
        #pragma unroll
        for (int j = 0; j < 8; ++j) tmp[j] = tile[c8 * 8 + j][oc];
        *(uint4*)(dst + (size_t)oc * R + c8 * 8) = *(uint4*)tmp;
    }
}

// ---------------- grouped expert GEMM v2 ----------------
// 64-token tiles, 256 threads (4 waves), 80 KiB LDS -> 2 blocks/CU.
// All staging via async global_load_lds (16B/lane), double-buffered, one barrier per step.
// Per-wave output tile 64x64 (acc[4][4] f32x4): 32 MFMA per 16 ds_read_b128.
// LDS swizzle: 16B slot index XOR'd with (row & 7) [128B rows] / (row & 3) [64B rows];
// applied on the *global source* side at staging (linear LDS dest) and on ds_read addrs
// (both-sides-or-neither rule for global_load_lds).
__global__ __launch_bounds__(256, 2) void moe_gemm_kernel(
    const bf16* __restrict__ xb, const bf16* __restrict__ keysT, const bf16* __restrict__ valuesT,
    const int* __restrict__ counts, const int* __restrict__ offsets,
    const int* __restrict__ btok, const float* __restrict__ bgate,
    float* __restrict__ out) {
    int e = blockIdx.y;
    int n = counts[e];
    int tile = blockIdx.x;
    if (tile * 64 >= n) return;
    int off = offsets[e];
    int tid = threadIdx.x;
    int lane = tid & 63, w = tid >> 6;
    int lr = lane & 15, lg = lane >> 4;

    __shared__ __attribute__((aligned(16))) char smem[81920];
    char* XA = smem;            // stage A: [2][64][64] bf16  (2 x 8 KiB)
    char* KA = smem + 16384;    // stage A: [2][256][64] bf16 (2 x 32 KiB)
    char* HB = smem;            // stage B: [64][256] bf16 swizzled (32 KiB)
    char* VT = smem + 32768;    // stage B: [2][256][32] bf16 (2 x 16 KiB)

    // ---- per-lane token/gate registers (no s_tok/s_gate LDS: keeps block at exactly 80 KiB) ----
    int tokR[4][4]; float gateR[4][4];
    #pragma unroll
    for (int ri = 0; ri < 4; ++ri)
        #pragma unroll
        for (int j = 0; j < 4; ++j) {
            int idxr = tile * 64 + ri * 16 + lg * 4 + j;
            bool val = idxr < n;
            int t = val ? btok[off + idxr] : 0;
            tokR[ri][j] = t & (NTOK - 1);
            float g = val ? bgate[off + idxr] : 0.f;
            gateR[ri][j] = (g == g) ? g : 0.f;   // defensive NaN scrub
        }

    // ---- staging geometry: 128-B rows (XA/KA): 8 slots of 16B, swz = slot ^ (row&7) ----
    int p8 = lane >> 3;                    // row within 8-row chunk
    int gsl = (lane & 7) ^ p8;             // pre-swizzled global slot for this lane
    int iA = tile * 64 + w * 16 + p8;
    int iB = iA + 8;
    int tokA = (iA < n ? btok[off + iA] : 0) & (NTOK - 1);
    int tokB = (iB < n ? btok[off + iB] : 0) & (NTOK - 1);
    const bf16* xs0 = xb + (size_t)tokA * DMODEL + gsl * 8;
    const bf16* xs1 = xb + (size_t)tokB * DMODEL + gsl * 8;
    const bf16* ksrc = keysT + (size_t)e * ESZ * DMODEL + (size_t)(w * 64 + p8) * DMODEL + gsl * 8;
    // 64-B rows (VT): 4 slots of 16B, swz = slot ^ (row&3)
    int p4 = lane >> 2;
    int g2 = (lane & 3) ^ (p4 & 3);
    const bf16* vsrc = valuesT + (size_t)e * DMODEL * ESZ + (size_t)(w * 64 + p4) * ESZ + g2 * 8;

    // =================== stage A: H = X[64][1024] @ K_e^T -> acc ===================
    f32x4 acc[4][4] = {};

    // prologue: stage kb=0 into buf0
    gl_lds16(xs0, XA + (w * 2 + 0) * 1024);
    gl_lds16(xs1, XA + (w * 2 + 1) * 1024);
    #pragma unroll
    for (int j = 0; j < 8; ++j)
        gl_lds16(ksrc + j * 8 * DMODEL, KA + (w * 8 + j) * 1024);
    __syncthreads();

    int buf = 0;
    for (int kb = 0; kb < 16; ++kb) {
        if (kb < 15) {                          // async prefetch next k-block
            int nk = kb + 1;
            char* xd = XA + (buf ^ 1) * 8192;
            char* kd = KA + (buf ^ 1) * 32768;
            gl_lds16(xs0 + nk * 64, xd + (w * 2 + 0) * 1024);
            gl_lds16(xs1 + nk * 64, xd + (w * 2 + 1) * 1024);
            #pragma unroll
            for (int j = 0; j < 8; ++j)
                gl_lds16(ksrc + j * 8 * DMODEL + nk * 64, kd + (w * 8 + j) * 1024);
        } else {                                // prefetch first VT tile (region = KA buf0 upper half, free at kb=15)
            #pragma unroll
            for (int j = 0; j < 4; ++j)
                gl_lds16(vsrc + j * 16 * ESZ, VT + (w * 4 + j) * 1024);
        }
        const char* XAb = XA + buf * 8192;
        const char* KAb = KA + buf * 32768;
        #pragma unroll
        for (int ks = 0; ks < 2; ++ks) {
            int sl = ((ks * 4 + lg) ^ (lr & 7)) << 4;
            bf16x8 a[4], b[4];
            #pragma unroll
            for (int ri = 0; ri < 4; ++ri)
                a[ri] = *(const bf16x8*)(XAb + (ri * 16 + lr) * 128 + sl);
            #pragma unroll
            for (int ci = 0; ci < 4; ++ci)
                b[ci] = *(const bf16x8*)(KAb + (w * 64 + ci * 16 + lr) * 128 + sl);
            #pragma unroll
            for (int ri = 0; ri < 4; ++ri)
                #pragma unroll
                for (int ci = 0; ci < 4; ++ci)
                    acc[ri][ci] = __builtin_amdgcn_mfma_f32_16x16x32_bf16(a[ri], b[ci], acc[ri][ci], 0, 0, 0);
        }
        __syncthreads();   // drains vmcnt (global_load_lds) + barrier
        buf ^= 1;
    }

    // =================== H = relu(acc) * gate -> LDS (swizzled [64][256]) ===================
    #pragma unroll
    for (int ri = 0; ri < 4; ++ri)
        #pragma unroll
        for (int j = 0; j < 4; ++j) {
            int row = ri * 16 + lg * 4 + j;
            int rx = row & 7;
            float gt = gateR[ri][j];
            char* hp = HB + row * 512 + (lr & 7) * 2;
            #pragma unroll
            for (int ci = 0; ci < 4; ++ci) {
                int slot = (w * 8 + ci * 2 + (lr >> 3)) ^ rx;
                *(bf16*)(hp + (slot << 4)) = __float2bfloat16(fmaxf(acc[ri][ci][j], 0.f) * gt);
            }
        }
    __syncthreads();

    // =================== stage B: Y = H[64][256] @ V_e -> atomic out ===================
    f32x4 acc2[4][4] = {};
    int vb = 0;
    for (int st = 0; st < 32; ++st) {          // vc = st>>3 (4 x 256 v-cols), hc = st&7 (8 x 32 h)
        int vc = st >> 3, hc = st & 7;
        if (st < 31) {
            int ns = st + 1;
            int nvc = ns >> 3, nhc = ns & 7;
            char* vd = VT + (vb ^ 1) * 16384;
            #pragma unroll
            for (int j = 0; j < 4; ++j)
                gl_lds16(vsrc + (size_t)nvc * 256 * ESZ + j * 16 * ESZ + nhc * 32,
                         vd + (w * 4 + j) * 1024);
        }
        const char* VTb = VT + vb * 16384;
        {
            bf16x8 a[4], b[4];
            #pragma unroll
            for (int ri = 0; ri < 4; ++ri)
                a[ri] = *(const bf16x8*)(HB + (ri * 16 + lr) * 512 + (((hc * 4 + lg) ^ (lr & 7)) << 4));
            #pragma unroll
            for (int ci = 0; ci < 4; ++ci)
                b[ci] = *(const bf16x8*)(VTb + (w * 64 + ci * 16 + lr) * 64 + ((lg ^ (lr & 3)) << 4));
            #pragma unroll
            for (int ri = 0; ri < 4; ++ri)
                #pragma unroll
                for (int ci = 0; ci < 4; ++ci)
                    acc2[ri][ci] = __builtin_amdgcn_mfma_f32_16x16x32_bf16(a[ri], b[ci], acc2[ri][ci], 0, 0, 0);
        }
        if (hc == 7) {   // finished K for this v-chunk: scatter-accumulate (tail rows have gate 0 -> add 0.0)
            #pragma unroll
            for (int ri = 0; ri < 4; ++ri)
                #pragma unroll
                for (int j = 0; j < 4; ++j) {
                    float* orow = out + (size_t)tokR[ri][j] * DMODEL + vc * 256 + w * 64 + lr;
                    #pragma unroll
                    for (int ci = 0; ci < 4; ++ci)
                        unsafeAtomicAdd(orow + ci * 16, acc2[ri][ci][j]);
                }
            f32x4 z = {0.f, 0.f, 0.f, 0.f};
            #pragma unroll
            for (int ri = 0; ri < 4; ++ri)
                #pragma unroll
                for (int ci = 0; ci < 4; ++ci)
                    acc2[ri][ci] = z;
        }
        __syncthreads();
        vb ^= 1;
    }
}

extern "C" void kernel_launch(void* const* d_in, const int* in_sizes, int n_in,
                              void* d_out, int out_size, void* d_ws, size_t ws_size,
                              hipStream_t stream) {
    const float* x      = (const float*)d_in[0];
    const float* keys   = (const float*)d_in[1];
    const float* values = (const float*)d_in[2];
    const float* esel   = (const float*)d_in[3];
    float* out = (float*)d_out;   // [8192][1024] f32 = 32 MiB, accumulated into directly

    // Workspace map — total exactly 51380224 B (proven-safe bound):
    uint8_t* ws = (uint8_t*)d_ws;
    int*   eidx     = (int*)(ws);                        // [8192][4]   131072 B
    float* egate    = (float*)(ws + 131072);             // [8192][4]   131072 B
    int*   btok     = (int*)(ws + 262144);               // [32768]     131072 B
    float* bgate    = (float*)(ws + 393216);             // [32768]     131072 B
    int*   counts   = (int*)(ws + 524288);               // [32]
    int*   offsets  = (int*)(ws + 524416);               // [32]
    int*   counts_q = (int*)(ws + 524544);               // [32][4]     512 B
    bf16*  keysT    = (bf16*)(ws + 1048576);             // 16 MiB: [32][256 h][1024 d]
    bf16*  valuesT  = (bf16*)(ws + 17825792);            // 16 MiB: [32][1024 v][256 h]
    bf16*  xbf16    = (bf16*)(ws + 34603008);            // 16 MiB: [8192][1024]  (ends at 51380224)

    hipMemsetAsync(out, 0, (size_t)NTOK * DMODEL * sizeof(float), stream);

    xconv_kernel<<<NTOK * DMODEL / 2048, 256, 0, stream>>>(x, xbf16);
    transpose_conv_kernel<<<dim3(16, 4, 32), 256, 0, stream>>>(values, valuesT, ESZ, DMODEL);
    transpose_conv_kernel<<<dim3(4, 16, 32), 256, 0, stream>>>(keys, keysT, DMODEL, ESZ);
    sel_kernel<<<NTOK / 4, 256, 0, stream>>>(x, esel, eidx, egate);
    hist_kernel<<<NEXP, 256, 0, stream>>>(eidx, counts, counts_q);
    scan_kernel<<<1, 64, 0, stream>>>(counts, offsets);
    compact_kernel<<<dim3(NEXP, 4), 64, 0, stream>>>(eidx, egate, offsets, counts_q, btok, bgate);
    moe_gemm_kernel<<<dim3(128, NEXP), 256, 0, stream>>>(xbf16, keysT, valuesT, counts, offsets,
                                                         btok, bgate, out);
}

// Round 3
// 438.462 us; speedup vs baseline: 1.4331x; 1.4331x over previous
//
#include <hip/hip_runtime.h>
#include <hip/hip_bf16.h>
#include <stdint.h>

#define DMODEL 1024
#define NEXP 32
#define ESZ 256
#define NTOK 8192
#define NH 4

typedef __hip_bfloat16 bf16;
typedef short bf16x8 __attribute__((ext_vector_type(8)));
typedef float f32x4 __attribute__((ext_vector_type(4)));

__device__ __forceinline__ void pack8(const float4& a, const float4& b, bf16* t) {
    t[0] = __float2bfloat16(a.x); t[1] = __float2bfloat16(a.y);
    t[2] = __float2bfloat16(a.z); t[3] = __float2bfloat16(a.w);
    t[4] = __float2bfloat16(b.x); t[5] = __float2bfloat16(b.y);
    t[6] = __float2bfloat16(b.z); t[7] = __float2bfloat16(b.w);
}

// ---------------- x f32 -> bf16 (hoists conversion out of the GEMM hot loop) ----------------
__global__ void xconv_kernel(const float* __restrict__ x, bf16* __restrict__ xb) {
    size_t i = ((size_t)blockIdx.x * 256 + threadIdx.x) * 8;
    float4 a = *(const float4*)(x + i);
    float4 b = *(const float4*)(x + i + 4);
    bf16 t8[8];
    pack8(a, b, t8);
    *(uint4*)(xb + i) = *(uint4*)t8;
}

// ---------------- selection (pure f32): logits -> top-4 -> gates (NO atomics) ----------------
__global__ void sel_kernel(const float* __restrict__ x, const float* __restrict__ esel,
                           int* __restrict__ eidx, float* __restrict__ egate) {
    int lane = threadIdx.x & 63;
    int wid = threadIdx.x >> 6;
    int t = blockIdx.x * 4 + wid;

    const float* xp = x + (size_t)t * DMODEL + lane * 16;
    float xv[16];
    *(float4*)&xv[0]  = *(const float4*)(xp);
    *(float4*)&xv[4]  = *(const float4*)(xp + 4);
    *(float4*)&xv[8]  = *(const float4*)(xp + 8);
    *(float4*)&xv[12] = *(const float4*)(xp + 12);

    __shared__ float sc[4][NEXP];
    for (int e = 0; e < NEXP; ++e) {
        const float* sp = esel + (size_t)e * DMODEL + lane * 16;
        float4 p0 = *(const float4*)(sp);
        float4 p1 = *(const float4*)(sp + 4);
        float4 p2 = *(const float4*)(sp + 8);
        float4 p3 = *(const float4*)(sp + 12);
        float s = xv[0]*p0.x + xv[1]*p0.y + xv[2]*p0.z + xv[3]*p0.w
                + xv[4]*p1.x + xv[5]*p1.y + xv[6]*p1.z + xv[7]*p1.w
                + xv[8]*p2.x + xv[9]*p2.y + xv[10]*p2.z + xv[11]*p2.w
                + xv[12]*p3.x + xv[13]*p3.y + xv[14]*p3.z + xv[15]*p3.w;
        #pragma unroll
        for (int o = 32; o > 0; o >>= 1) s += __shfl_xor(s, o, 64);
        if (lane == 0) sc[wid][e] = s;
    }

    if (lane == 0) {
        // strict > scan: lowest index wins ties (matches lax.top_k; sigmoid is monotone)
        for (int j = 0; j < NH; ++j) {
            float m = -1e30f; int mi = 0;
            for (int e = 0; e < NEXP; ++e) {
                float v = sc[wid][e];
                if (v > m) { m = v; mi = e; }
            }
            sc[wid][mi] = -1e30f;
            float g = 1.f / (1.f + expf(-m));   // sigmoid of logit
            eidx[t * NH + j] = mi;
            egate[t * NH + j] = g;
        }
    }
}

// ---------------- per-expert histogram (contention-free): counts + quarter counts ----------------
__global__ void hist_kernel(const int* __restrict__ eidx, int* __restrict__ counts,
                            int* __restrict__ counts_q) {
    int e = blockIdx.x;            // 32 blocks, one per expert
    int w = threadIdx.x >> 6;      // wave = quarter of the 32768 entries
    int lane = threadIdx.x & 63;
    const int* p = eidx + w * 8192;
    int cnt = 0;
    for (int it = 0; it < 128; ++it)
        cnt += (p[it * 64 + lane] == e);
    #pragma unroll
    for (int o = 32; o > 0; o >>= 1) cnt += __shfl_xor(cnt, o, 64);
    __shared__ int s_q[4];
    if (lane == 0) s_q[w] = cnt;
    __syncthreads();
    if (threadIdx.x == 0) {
        counts[e] = s_q[0] + s_q[1] + s_q[2] + s_q[3];
        counts_q[e * 4 + 0] = s_q[0];
        counts_q[e * 4 + 1] = s_q[1];
        counts_q[e * 4 + 2] = s_q[2];
        counts_q[e * 4 + 3] = s_q[3];
    }
}

// ---------------- tiny exclusive scan over 32 counts ----------------
__global__ void scan_kernel(const int* __restrict__ counts, int* __restrict__ offsets) {
    if (threadIdx.x == 0) {
        int s = 0;
        for (int e = 0; e < NEXP; ++e) { offsets[e] = s; s += counts[e]; }
    }
}

// ---------------- deterministic ballot compaction into buckets (NO atomics) ----------------
__global__ void compact_kernel(const int* __restrict__ eidx, const float* __restrict__ egate,
                               const int* __restrict__ offsets, const int* __restrict__ counts_q,
                               int* __restrict__ btok, float* __restrict__ bgate) {
    int e = blockIdx.x;   // 32
    int q = blockIdx.y;   // 4
    int lane = threadIdx.x;  // block = 64 (one wave)
    int base = offsets[e];
    #pragma unroll
    for (int k = 0; k < 4; ++k) if (k < q) base += counts_q[e * 4 + k];
    const int* p = eidx + q * 8192;
    const float* g = egate + q * 8192;
    int v = p[lane];
    for (int it = 0; it < 128; ++it) {
        int v_next = (it < 127) ? p[(it + 1) * 64 + lane] : 0;   // prefetch
        unsigned long long m = __ballot(v == e);
        if (v == e) {
            int i = it * 64 + lane;
            int pos = base + __popcll(m & ((1ull << lane) - 1ull));
            btok[pos] = (q * 8192 + i) >> 2;      // token index
            bgate[pos] = g[i];
        }
        base += __popcll(m);
        v = v_next;
    }
}

// ---------------- per-expert transpose+convert: f32 in[e][R][C] -> bf16 out[e][C][R] ----------------
__global__ void transpose_conv_kernel(const float* __restrict__ in, bf16* __restrict__ out,
                                      int R, int C) {
    __shared__ bf16 tile[64][72];
    int e = blockIdx.z, tr = blockIdx.y, tc = blockIdx.x;
    const float* src = in + ((size_t)e * R + tr * 64) * C + tc * 64;
    #pragma unroll
    for (int i = 0; i < 2; ++i) {
        int c = threadIdx.x + 256 * i;
        int r = c >> 3, c8 = c & 7;
        float4 p0 = *(const float4*)(src + (size_t)r * C + c8 * 8);
        float4 p1 = *(const float4*)(src + (size_t)r * C + c8 * 8 + 4);
        bf16 t8[8];
        pack8(p0, p1, t8);
        *(uint4*)&tile[r][c8 * 8] = *(uint4*)t8;
    }
    __syncthreads();
    bf16* dst = out + ((size_t)e * C + tc * 64) * R + tr * 64;
    #pragma unroll
    for (int i = 0; i < 2; ++i) {
        int c = threadIdx.x + 256 * i;
        int oc = c >> 3, c8 = c & 7;
        bf16 tmp[8];
        #pragma unroll
        for (int j = 0; j < 8; ++j) tmp[j] = tile[c8 * 8 + j][oc];
        *(uint4*)(dst + (size_t)oc * R + c8 * 8) = *(uint4*)tmp;
    }
}

// ---------------- grouped expert GEMM: Y += gate * relu(Xg @ K_e) @ V_e ----------------
// v3 = proven v1 structure (52.7 KB LDS -> 3 blocks/CU) with TWO aux changes only:
//   (1) X staged from precomputed bf16 (no in-loop f32->bf16 cvt, half the X bytes)
//   (2) scatter-accumulate straight into `out` (no yacc workspace, no finalize pass)
// block = 256 threads (4 waves), tile = 64 tokens. Stage A: H[64][256]; Stage B: Y[64][1024].
__global__ __launch_bounds__(256) void moe_gemm_kernel(
    const bf16* __restrict__ xb, const bf16* __restrict__ keysT, const bf16* __restrict__ valuesT,
    const int* __restrict__ counts, const int* __restrict__ offsets,
    const int* __restrict__ btok, const float* __restrict__ bgate,
    float* __restrict__ out) {
    int e = blockIdx.y;
    int n = counts[e];
    int tile = blockIdx.x;
    if (tile * 64 >= n) return;
    int off = offsets[e];
    int tid = threadIdx.x;
    int lane = tid & 63;
    int w = tid >> 6;

    // LDS: stage A uses Xg[64][72] @0 (9216 B) + KT[256][72] @9216 (36864 B) = 46080 B
    //      stage B uses H[64][264] @0 (33792 B) + VT[128][72] @33792 (18432 B) = 52224 B
    __shared__ __align__(16) unsigned char smem[52224];
    bf16* Xg = (bf16*)smem;
    bf16* KT = (bf16*)(smem + 9216);
    bf16* H  = (bf16*)smem;
    bf16* VT = (bf16*)(smem + 33792);
    __shared__ int s_tok[64];
    __shared__ float s_gate[64];

    if (tid < 64) {
        int idxr = tile * 64 + tid;
        bool valid = idxr < n;
        int tok = valid ? btok[off + idxr] : 0;
        s_tok[tid] = tok & (NTOK - 1);           // defensive mask
        float g = valid ? bgate[off + idxr] : 0.f;
        s_gate[tid] = (g == g) ? g : 0.f;        // defensive NaN scrub
    }
    __syncthreads();

    int lr = lane & 15;   // fragment row/col index
    int lg = lane >> 4;   // quad
    int c16 = tid & 7;
    int r0 = tid >> 3;    // 0..31

    f32x4 acc[16] = {};   // wave w: H rows [16w,16w+16) x cols [0,256)

    const bf16* kbase = keysT + (size_t)e * ESZ * DMODEL;
    const bf16* xrA = xb + (size_t)s_tok[r0] * DMODEL;
    const bf16* xrB = xb + (size_t)s_tok[r0 + 32] * DMODEL;

    for (int kb = 0; kb < 16; ++kb) {
        // stage Xg [64][64] — already bf16, straight 16B copies
        *(uint4*)&Xg[r0 * 72 + c16 * 8] =
            *(const uint4*)(xrA + kb * 64 + c16 * 8);
        *(uint4*)&Xg[(r0 + 32) * 72 + c16 * 8] =
            *(const uint4*)(xrB + kb * 64 + c16 * 8);
        // stage KT [256][64] (keysT rows are contiguous in d, already bf16)
        #pragma unroll
        for (int i = 0; i < 8; ++i) {
            int h = r0 + 32 * i;
            *(uint4*)&KT[h * 72 + c16 * 8] =
                *(const uint4*)(kbase + (size_t)h * DMODEL + kb * 64 + c16 * 8);
        }
        __syncthreads();
        #pragma unroll
        for (int ks = 0; ks < 2; ++ks) {
            bf16x8 a = *(bf16x8*)&Xg[(w * 16 + lr) * 72 + ks * 32 + lg * 8];
            #pragma unroll
            for (int ct = 0; ct < 16; ++ct) {
                bf16x8 b = *(bf16x8*)&KT[(ct * 16 + lr) * 72 + ks * 32 + lg * 8];
                acc[ct] = __builtin_amdgcn_mfma_f32_16x16x32_bf16(a, b, acc[ct], 0, 0, 0);
            }
        }
        __syncthreads();
    }

    // relu + gate, f32 -> bf16 into H
    int rbase = w * 16 + lg * 4;
    {
        float g0 = s_gate[rbase + 0], g1 = s_gate[rbase + 1];
        float g2 = s_gate[rbase + 2], g3 = s_gate[rbase + 3];
        #pragma unroll
        for (int ct = 0; ct < 16; ++ct) {
            int col = ct * 16 + lr;
            H[(rbase + 0) * 264 + col] = __float2bfloat16(fmaxf(acc[ct][0], 0.f) * g0);
            H[(rbase + 1) * 264 + col] = __float2bfloat16(fmaxf(acc[ct][1], 0.f) * g1);
            H[(rbase + 2) * 264 + col] = __float2bfloat16(fmaxf(acc[ct][2], 0.f) * g2);
            H[(rbase + 3) * 264 + col] = __float2bfloat16(fmaxf(acc[ct][3], 0.f) * g3);
        }
    }
    __syncthreads();

    // stage B: Y[64][1024] in v-chunks of 128
    const bf16* vbase = valuesT + (size_t)e * DMODEL * ESZ;
    for (int vc = 0; vc < 8; ++vc) {
        f32x4 yr[8] = {};
        #pragma unroll
        for (int hc = 0; hc < 4; ++hc) {
            // stage VT chunk [128 v][64 h] (valuesT rows contiguous in h)
            #pragma unroll
            for (int i = 0; i < 4; ++i) {
                int vr = r0 + 32 * i;
                *(uint4*)&VT[vr * 72 + c16 * 8] =
                    *(const uint4*)(vbase + (size_t)(vc * 128 + vr) * ESZ + hc * 64 + c16 * 8);
            }
            __syncthreads();
            #pragma unroll
            for (int ks = 0; ks < 2; ++ks) {
                bf16x8 a = *(bf16x8*)&H[(w * 16 + lr) * 264 + hc * 64 + ks * 32 + lg * 8];
                #pragma unroll
                for (int ct = 0; ct < 8; ++ct) {
                    bf16x8 b = *(bf16x8*)&VT[(ct * 16 + lr) * 72 + ks * 32 + lg * 8];
                    yr[ct] = __builtin_amdgcn_mfma_f32_16x16x32_bf16(a, b, yr[ct], 0, 0, 0);
                }
            }
            __syncthreads();
        }
        // scatter-accumulate straight into the output (memset'd at launch)
        #pragma unroll
        for (int ct = 0; ct < 8; ++ct) {
            int v = vc * 128 + ct * 16 + lr;
            #pragma unroll
            for (int r = 0; r < 4; ++r) {
                int row = rbase + r;
                if (tile * 64 + row < n) {
                    unsafeAtomicAdd(&out[(size_t)s_tok[row] * DMODEL + v], yr[ct][r]);
                }
            }
        }
    }
}

extern "C" void kernel_launch(void* const* d_in, const int* in_sizes, int n_in,
                              void* d_out, int out_size, void* d_ws, size_t ws_size,
                              hipStream_t stream) {
    const float* x      = (const float*)d_in[0];
    const float* keys   = (const float*)d_in[1];
    const float* values = (const float*)d_in[2];
    const float* esel   = (const float*)d_in[3];
    float* out = (float*)d_out;   // [8192][1024] f32 = 32 MiB, accumulated into directly

    // Workspace map — total exactly 51380224 B (proven-safe bound):
    uint8_t* ws = (uint8_t*)d_ws;
    int*   eidx     = (int*)(ws);                        // [8192][4]   131072 B
    float* egate    = (float*)(ws + 131072);             // [8192][4]   131072 B
    int*   btok     = (int*)(ws + 262144);               // [32768]     131072 B
    float* bgate    = (float*)(ws + 393216);             // [32768]     131072 B
    int*   counts   = (int*)(ws + 524288);               // [32]
    int*   offsets  = (int*)(ws + 524416);               // [32]
    int*   counts_q = (int*)(ws + 524544);               // [32][4]     512 B
    bf16*  keysT    = (bf16*)(ws + 1048576);             // 16 MiB: [32][256 h][1024 d]
    bf16*  valuesT  = (bf16*)(ws + 17825792);            // 16 MiB: [32][1024 v][256 h]
    bf16*  xbf16    = (bf16*)(ws + 34603008);            // 16 MiB: [8192][1024]  (ends at 51380224)

    hipMemsetAsync(out, 0, (size_t)NTOK * DMODEL * sizeof(float), stream);

    xconv_kernel<<<NTOK * DMODEL / 2048, 256, 0, stream>>>(x, xbf16);
    transpose_conv_kernel<<<dim3(16, 4, 32), 256, 0, stream>>>(values, valuesT, ESZ, DMODEL);
    transpose_conv_kernel<<<dim3(4, 16, 32), 256, 0, stream>>>(keys, keysT, DMODEL, ESZ);
    sel_kernel<<<NTOK / 4, 256, 0, stream>>>(x, esel, eidx, egate);
    hist_kernel<<<NEXP, 256, 0, stream>>>(eidx, counts, counts_q);
    scan_kernel<<<1, 64, 0, stream>>>(counts, offsets);
    compact_kernel<<<dim3(NEXP, 4), 64, 0, stream>>>(eidx, egate, offsets, counts_q, btok, bgate);
    moe_gemm_kernel<<<dim3(128, NEXP), 256, 0, stream>>>(xbf16, keysT, valuesT, counts, offsets,
                                                         btok, bgate, out);
}